// Round 5
// baseline (13.009 us; speedup 1.0000x reference)
//
#include <hip/hip_runtime.h>

// OriginalConjunctionLayer: res_bar[b,n] = prod_d (1 - (1-x[b,d]) * (W[d,n] > 0.5))
//                          = prod_{d : W[d,n] > 0.5} x[b,d];  m_out = ones.
//
// Two-kernel split (dispatch in graph is ~free; critical path is not):
//  A: all 128 blocks speculatively store ones over the whole output (always
//     correct for m_out; correct for res_bar iff no W > 0.5). Blocks 0-15
//     each scan a 16 KB slice of W (1 uint4/thread, raw-bit compare:
//     non-negative W > 0.5f <=> bits > 0x3F000000; negative W spuriously
//     takes the general path, staying exact) and write 16 per-wave flag
//     words each -> flags[0..255] in d_ws, rewritten every call.
//  B: each wave loads the 256 flag words (1 uint4/lane, L2), __any-reduces,
//     returns when zero (no x traffic at all). Otherwise: exact general path
//     (8 KB LDS bitmask of W, per-32-d chunk skip) overwrites res_bar.
//     A's stores complete at the kernel boundary -> WAW-safe.

#define DDIM 1024
#define NRULE 64
#define WPN (DDIM / 32)          // 32 mask words per rule column
#define ROWS 32                  // batch rows per B-block -> 128 blocks at B=4096
#define NFLAGS 256               // 16 scanning blocks x 16 waves

__global__ void __launch_bounds__(1024) conj_store_scan_kernel(
    const float* __restrict__ W, float* __restrict__ out,
    unsigned* __restrict__ flags, int B) {
    int tid  = threadIdx.x;
    int lane = tid & 63;
    int wv   = tid >> 6;                       // wave 0..15
    int gt   = blockIdx.x * 1024 + tid;

    // ---- Speculative ones over the ENTIRE output (res_bar + m_out, 2 MB) ----
    const float4 one4 = make_float4(1.0f, 1.0f, 1.0f, 1.0f);
    reinterpret_cast<float4*>(out)[gt] = one4;   // 131072 float4 == 2*B*NRULE

    // ---- Blocks 0-15: scan 16 KB slice of W, 1 uint4 per thread ----
    if (blockIdx.x < 16) {
        uint4 v = reinterpret_cast<const uint4*>(W)[gt];   // gt < 16384
        unsigned mx = v.x > v.y ? v.x : v.y;
        mx = mx > v.z ? mx : v.z;
        mx = mx > v.w ? mx : v.w;
        int any = __any(mx > 0x3F000000u);     // bits(0.5f)
        if (lane == 0) flags[blockIdx.x * 16 + wv] = (unsigned)any;
    }
}

__global__ void __launch_bounds__(256) conj_general_kernel(
    const float* __restrict__ x, const float* __restrict__ W,
    const unsigned* __restrict__ flags, float* __restrict__ out, int B) {
    __shared__ unsigned bm_lds[WPN * NRULE];   // 8 KB bitmask (general path)

    int tid  = threadIdx.x;
    int lane = tid & 63;
    int wv   = tid >> 6;                       // wave 0..3

    // ---- Flag check: each wave loads all 256 words (1 uint4 per lane) ----
    uint4 f = reinterpret_cast<const uint4*>(flags)[lane];   // 64 lanes x 4 = 256
    if (!__any((f.x | f.y | f.z | f.w) != 0u)) return;       // fast path

    // ---- General path: binarize W into LDS bitmask (exact float compare) ----
    // thread (wv, lane=n) builds words w = wv*8 + k; lanes span n -> each
    // inner load is a contiguous 256 B segment per wave (coalesced).
    #pragma unroll
    for (int k = 0; k < 8; ++k) {
        int w = wv * 8 + k;
        unsigned word = 0u;
        #pragma unroll
        for (int j = 0; j < 32; ++j) {
            word |= (W[(w * 32 + j) * NRULE + lane] > 0.5f) ? (1u << j) : 0u;
        }
        bm_lds[w * NRULE + lane] = word;
    }
    __syncthreads();

    // ---- Per-row product with per-chunk skip (8 rows per wave) ----
    for (int rr = 0; rr < ROWS / 4; ++rr) {
        int b = blockIdx.x * ROWS + wv * (ROWS / 4) + rr;
        if (b >= B) break;
        const float* xrow = x + (size_t)b * DDIM;
        float acc = 1.0f;
        for (int w = 0; w < WPN; ++w) {
            unsigned word = bm_lds[w * NRULE + lane];   // bank = n%32: 2-way, free
            if (__any(word != 0u)) {
                #pragma unroll
                for (int j = 0; j < 32; j += 4) {
                    float4 xv = *reinterpret_cast<const float4*>(xrow + w * 32 + j);
                    if (word & (1u << (j + 0))) acc *= xv.x;
                    if (word & (1u << (j + 1))) acc *= xv.y;
                    if (word & (1u << (j + 2))) acc *= xv.z;
                    if (word & (1u << (j + 3))) acc *= xv.w;
                }
            }
        }
        out[(size_t)b * NRULE + lane] = acc;            // coalesced 256 B / wave
    }
}

extern "C" void kernel_launch(void* const* d_in, const int* in_sizes, int n_in,
                              void* d_out, int out_size, void* d_ws, size_t ws_size,
                              hipStream_t stream) {
    const float* x = (const float*)d_in[0];
    // d_in[1] is m (ignored: missing_aware=False)
    const float* W = (const float*)d_in[2];
    float* out = (float*)d_out;
    unsigned* flags = (unsigned*)d_ws;          // 256 words, rewritten every call

    int B = in_sizes[0] / DDIM;                 // 4096
    int nblocks = (B + ROWS - 1) / ROWS;        // 128

    hipLaunchKernelGGL(conj_store_scan_kernel, dim3(nblocks), dim3(1024), 0,
                       stream, W, out, flags, B);
    hipLaunchKernelGGL(conj_general_kernel, dim3(nblocks), dim3(256), 0,
                       stream, x, W, flags, out, B);
}

// Round 6
// 11.742 us; speedup vs baseline: 1.1079x; 1.1079x over previous
//
#include <hip/hip_runtime.h>

// OriginalConjunctionLayer: res_bar[b,n] = prod_d (1 - (1-x[b,d]) * (W[d,n] > 0.5))
//                          = prod_{d : W[d,n] > 0.5} x[b,d];  m_out = ones.
//
// Single fused kernel (R4 structure — the 2-kernel split costs ~3us of
// dependent-dispatch serialization, measured R5):
//   1. Issue the block-wide W scan loads (16 uint4/thread, raw-bit compare:
//      non-negative floats W > 0.5f <=> bits > 0x3F000000; negative W
//      spuriously takes the general path, which stays exact).
//   2. Speculatively store ones to BOTH m_out (always correct) and res_bar
//      (correct when no W > 0.5 — true for W = 0.5*U[0,1)).
//   3. Ballot + one barrier -> block-uniform flag; fast path exits.
//   4. General path (exact for arbitrary W): binarize W into an 8 KB LDS
//      bitmask (barrier also orders the speculative stores -> WAW-safe),
//      then per-32-d chunk product skipping x loads when the wave's mask
//      words are all zero, overwriting res_bar.

#define DDIM 1024
#define NRULE 64
#define WPN (DDIM / 32)        // 32 mask words per rule column
#define ROWS 32                // batch rows per block -> 128 blocks at B=4096
#define TPB 1024               // 16 waves
#define NWAVES (TPB / 64)

__device__ __forceinline__ unsigned umax_(unsigned a, unsigned b) {
    return a > b ? a : b;
}

__global__ void __launch_bounds__(TPB) conj_fused_kernel(
    const float* __restrict__ x, const float* __restrict__ W,
    float* __restrict__ out, int B) {
    __shared__ unsigned bm_lds[WPN * NRULE];   // 8 KB bitmask (general path)
    __shared__ int s_flag[NWAVES];

    int tid  = threadIdx.x;
    int lane = tid & 63;
    int wv   = tid >> 6;                       // wave 0..15

    // ---- W scan loads first (get them in flight; 16 independent uint4) ----
    const uint4* W4 = reinterpret_cast<const uint4*>(W);
    unsigned mxu = 0u;
    #pragma unroll 16
    for (int i = tid; i < (DDIM * NRULE) / 4; i += TPB) {
        uint4 v = W4[i];
        mxu = umax_(umax_(mxu, v.x), umax_(v.y, umax_(v.z, v.w)));
    }

    // ---- Speculative stores: res_bar = 1 and m_out = 1 (fire-and-forget) ----
    const float4 one4 = make_float4(1.0f, 1.0f, 1.0f, 1.0f);
    size_t blk_elems = (size_t)blockIdx.x * ROWS * NRULE;     // 2048 floats
    if (tid < 512) {
        reinterpret_cast<float4*>(out + blk_elems)[tid] = one4;
    } else {
        reinterpret_cast<float4*>(out + (size_t)B * NRULE + blk_elems)[tid - 512] = one4;
    }

    // ---- Block-uniform "any W > 0.5" flag ----
    int any = __any(mxu > 0x3F000000u);        // bits(0.5f) = 0x3F000000
    if (lane == 0) s_flag[wv] = any;
    __syncthreads();
    // 16 addrs x 4-lane same-address broadcast: conflict-free single LDS read
    int flag = __any(s_flag[lane & (NWAVES - 1)] != 0);

    if (!flag) return;   // fast path: ones already stored, no x traffic

    // ---- General path: binarize W into LDS bitmask (exact float compare) ----
    // thread (wv, lane=n) builds words w = wv*2 + k; lanes span n -> each
    // inner load is a contiguous 256 B segment per wave (coalesced).
    #pragma unroll
    for (int k = 0; k < WPN / NWAVES; ++k) {
        int w = wv * (WPN / NWAVES) + k;
        unsigned word = 0u;
        #pragma unroll
        for (int j = 0; j < 32; ++j) {
            word |= (W[(w * 32 + j) * NRULE + lane] > 0.5f) ? (1u << j) : 0u;
        }
        bm_lds[w * NRULE + lane] = word;
    }
    __syncthreads();   // also orders the speculative res_bar stores (WAW-safe)

    // ---- Per-row product with per-chunk skip (2 rows per wave) ----
    for (int rr = 0; rr < ROWS / NWAVES; ++rr) {
        int b = blockIdx.x * ROWS + wv * (ROWS / NWAVES) + rr;
        if (b >= B) break;
        const float* xrow = x + (size_t)b * DDIM;
        float acc = 1.0f;
        for (int w = 0; w < WPN; ++w) {
            unsigned word = bm_lds[w * NRULE + lane];   // bank = n%32: 2-way, free
            if (__any(word != 0u)) {
                #pragma unroll
                for (int j = 0; j < 32; j += 4) {
                    float4 xv = *reinterpret_cast<const float4*>(xrow + w * 32 + j);
                    if (word & (1u << (j + 0))) acc *= xv.x;
                    if (word & (1u << (j + 1))) acc *= xv.y;
                    if (word & (1u << (j + 2))) acc *= xv.z;
                    if (word & (1u << (j + 3))) acc *= xv.w;
                }
            }
        }
        out[(size_t)b * NRULE + lane] = acc;            // coalesced 256 B / wave
    }
}

extern "C" void kernel_launch(void* const* d_in, const int* in_sizes, int n_in,
                              void* d_out, int out_size, void* d_ws, size_t ws_size,
                              hipStream_t stream) {
    const float* x = (const float*)d_in[0];
    // d_in[1] is m (ignored: missing_aware=False)
    const float* W = (const float*)d_in[2];
    float* out = (float*)d_out;

    int B = in_sizes[0] / DDIM;                 // 4096
    int nblocks = (B + ROWS - 1) / ROWS;        // 128
    hipLaunchKernelGGL(conj_fused_kernel, dim3(nblocks), dim3(TPB), 0, stream,
                       x, W, out, B);
}

// Round 7
// 10.419 us; speedup vs baseline: 1.2485x; 1.1270x over previous
//
#include <hip/hip_runtime.h>

// OriginalConjunctionLayer: res_bar[b,n] = prod_d (1 - (1-x[b,d]) * (W[d,n] > 0.5))
//                          = prod_{d : W[d,n] > 0.5} x[b,d];  m_out = ones.
//
// Single fused kernel, speculative-store structure (R4 — best measured).
// Ordering matters: stores issue FIRST (fire-and-forget; kernel-end drain is
// the tail), W-scan loads fill their shadow. R6's load-first reorder cost 2us.
//   1. Every block immediately stores ones to BOTH its m_out slice (always
//      correct) and its res_bar slice (correct for the all-mask-zero case).
//   2. Block scans W's raw bits (non-negative floats: W > 0.5f <=> bits >
//      0x3F000000; negative W spuriously takes the general path, stays exact).
//   3. Fast path (no W > 0.5, true for W = 0.5*U[0,1)): exit — stores already
//      in flight, no x traffic at all.
//   4. General path (exact for arbitrary W): binarize W into an 8 KB LDS
//      bitmask, __syncthreads (drains the speculative stores -> WAW-safe),
//      then per-32-d chunk product that skips x loads when the wave's mask
//      words are all zero, overwriting res_bar with the computed value.

#define DDIM 1024
#define NRULE 64
#define WPN (DDIM / 32)        // 32 mask words per rule column
#define ROWS 32                // batch rows per block -> 128 blocks at B=4096
#define TPB 1024               // 16 waves
#define NWAVES (TPB / 64)

__device__ __forceinline__ unsigned umax_(unsigned a, unsigned b) {
    return a > b ? a : b;
}

__global__ void __launch_bounds__(TPB) conj_fused_kernel(
    const float* __restrict__ x, const float* __restrict__ W,
    float* __restrict__ out, int B) {
    __shared__ unsigned bm_lds[WPN * NRULE];   // 8 KB bitmask (general path)
    __shared__ int s_flag[NWAVES];

    int tid  = threadIdx.x;
    int lane = tid & 63;
    int wv   = tid >> 6;                       // wave 0..15

    // ---- Speculative stores FIRST: m_out = 1 (always) and res_bar = 1 ----
    // (res_bar is overwritten by the general path after a barrier if needed.)
    const float4 one4 = make_float4(1.0f, 1.0f, 1.0f, 1.0f);
    size_t blk_elems = (size_t)blockIdx.x * ROWS * NRULE;     // 2048 floats
    if (tid < 512) {
        reinterpret_cast<float4*>(out + blk_elems)[tid] = one4;
    } else {
        reinterpret_cast<float4*>(out + (size_t)B * NRULE + blk_elems)[tid - 512] = one4;
    }

    // ---- Block-wide "any W > 0.5" via raw-bit compare (16 uint4 / thread) --
    const uint4* W4 = reinterpret_cast<const uint4*>(W);
    unsigned mxu = 0u;
    #pragma unroll 16
    for (int i = tid; i < (DDIM * NRULE) / 4; i += TPB) {
        uint4 v = W4[i];
        mxu = umax_(umax_(mxu, v.x), umax_(v.y, umax_(v.z, v.w)));
    }
    int any = __any(mxu > 0x3F000000u);        // bits(0.5f) = 0x3F000000
    if (lane == 0) s_flag[wv] = any;
    __syncthreads();
    int flag = 0;
    #pragma unroll
    for (int k = 0; k < NWAVES; ++k) flag |= s_flag[k];

    if (!flag) return;   // fast path: ones already stored, no x traffic

    // ---- General path: binarize W into LDS bitmask (exact float compare) ----
    // thread (wv, lane=n) builds words w = wv*2 + k; lanes span n -> each
    // inner load is a contiguous 256 B segment per wave (coalesced).
    #pragma unroll
    for (int k = 0; k < WPN / NWAVES; ++k) {
        int w = wv * (WPN / NWAVES) + k;
        unsigned word = 0u;
        #pragma unroll
        for (int j = 0; j < 32; ++j) {
            word |= (W[(w * 32 + j) * NRULE + lane] > 0.5f) ? (1u << j) : 0u;
        }
        bm_lds[w * NRULE + lane] = word;
    }
    __syncthreads();   // also orders the speculative res_bar stores (WAW-safe)

    // ---- Per-row product with per-chunk skip (2 rows per wave) ----
    for (int rr = 0; rr < ROWS / NWAVES; ++rr) {
        int b = blockIdx.x * ROWS + wv * (ROWS / NWAVES) + rr;
        if (b >= B) break;
        const float* xrow = x + (size_t)b * DDIM;
        float acc = 1.0f;
        for (int w = 0; w < WPN; ++w) {
            unsigned word = bm_lds[w * NRULE + lane];   // bank = n%32: 2-way, free
            if (__any(word != 0u)) {
                #pragma unroll
                for (int j = 0; j < 32; j += 4) {
                    float4 xv = *reinterpret_cast<const float4*>(xrow + w * 32 + j);
                    if (word & (1u << (j + 0))) acc *= xv.x;
                    if (word & (1u << (j + 1))) acc *= xv.y;
                    if (word & (1u << (j + 2))) acc *= xv.z;
                    if (word & (1u << (j + 3))) acc *= xv.w;
                }
            }
        }
        out[(size_t)b * NRULE + lane] = acc;            // coalesced 256 B / wave
    }
}

extern "C" void kernel_launch(void* const* d_in, const int* in_sizes, int n_in,
                              void* d_out, int out_size, void* d_ws, size_t ws_size,
                              hipStream_t stream) {
    const float* x = (const float*)d_in[0];
    // d_in[1] is m (ignored: missing_aware=False)
    const float* W = (const float*)d_in[2];
    float* out = (float*)d_out;

    int B = in_sizes[0] / DDIM;                 // 4096
    int nblocks = (B + ROWS - 1) / ROWS;        // 128
    hipLaunchKernelGGL(conj_fused_kernel, dim3(nblocks), dim3(TPB), 0, stream,
                       x, W, out, B);
}